// Round 3
// baseline (625.016 us; speedup 1.0000x reference)
//
#include <hip/hip_runtime.h>
#include <stdint.h>

#define HW    16384
#define NB    64
#define W2    130           // padded spatial dim (1-px halo each side)
#define PXS   (W2*W2)       // 16900 pixels per padded plane
#define WQH   70144         // fp16 weight halves per sample (frag-ordered)
#define EPSB  1e-5f

typedef _Float16 h8  __attribute__((ext_vector_type(8)));
typedef _Float16 h4  __attribute__((ext_vector_type(4)));
typedef float    f16v __attribute__((ext_vector_type(16)));
typedef float    f4  __attribute__((ext_vector_type(4)));
typedef h8 uh8 __attribute__((aligned(4)));
typedef h4 uh4 __attribute__((aligned(4)));
typedef f4 uf4 __attribute__((aligned(4)));

// ---------------------------------------------------------------------------
// prep_w: gather per-sample hypernet weights, fold BN scale, convert fp16,
// and write in EXACT mfma_32x32x16_f16 A-fragment order:
//   per layer, frame f = (tap*KST + kstep); within frame, lane(0..63) holds
//   8 halves: w[co = lane&31][c = kstep*16 + (lane>>5)*8 + e]  (0-padded).
// One thread produces one lane-frag (8 halves, one 16B store).
// Frames/layer: L0-2: 9, L3-8: 18, L9(1x1): 2. Frag offsets FO[] below.
// Also emits fp32 bias[l*32+co] = beta - mu*scale (0 for padded co / L9).
// ---------------------------------------------------------------------------
__global__ void prep_w(const float* __restrict__ w1, const float* __restrict__ w2,
                       const float* __restrict__ w3, const float* __restrict__ w4,
                       const float* __restrict__ g,  const float* __restrict__ be,
                       const float* __restrict__ mu, const float* __restrict__ va,
                       _Float16* __restrict__ wq, float* __restrict__ bias)
{
    const int FO[11]   = {0,576,1152,1728,2880,4032,5184,6336,7488,8640,8768};
    const int start[10]= {0,1080,2376,3672,8424,13608,16200,20952,26136,28728};
    const int COt[10]  = {12,12,12,24,24,12,24,24,12,11};
    const int CIt[10]  = {10,12,12,22,24,24,22,24,24,22};
    const int bnoff[10]= {0,12,24,36,60,84,96,120,144,0};
    const int KST[10]  = {1,1,1,2,2,2,2,2,2,2};

    long tid = (long)blockIdx.x * 256 + threadIdx.x;
    long total = (long)NB * 8768, stride = (long)gridDim.x * 256;
    for (long idx = tid; idx < total; idx += stride) {
        int b = (int)(idx / 8768), i = (int)(idx - (long)b * 8768);
        int l = 9; while (i < FO[l]) --l;
        int j = i - FO[l];
        int f = j >> 6, lane = j & 63;
        int ks = (KST[l] == 2) ? (f & 1) : 0;
        int s  = (KST[l] == 2) ? (f >> 1) : f;      // 3x3 tap index (0 for L9)
        int co = lane & 31, hi = lane >> 5;
        int CO = COt[l], CI = CIt[l];
        float scale = 1.f;
        if (l < 9 && co < CO) {
            int bi = bnoff[l] + co;
            scale = g[bi] * rsqrtf(va[bi] + EPSB);
        }
        int c0 = ks * 16 + hi * 8;
        __attribute__((aligned(16))) _Float16 vals[8];
#pragma unroll
        for (int e = 0; e < 8; ++e) {
            int c = c0 + e; float wv = 0.f;
            if (co < CO && c < CI) {
                int p = (l < 9) ? start[l] + (co * CI + c) * 9 + s
                                : start[9] + co * CI + c;
                const float* src; long si;
                if      (p <  3672) { src = w1; si = (long)b *  3672 + p; }
                else if (p < 16200) { src = w2; si = (long)b * 12528 + (p -  3672); }
                else if (p < 28728) { src = w3; si = (long)b * 12528 + (p - 16200); }
                else                { src = w4; si = (long)b *   242 + (p - 28728); }
                wv = src[si] * scale;
            }
            vals[e] = (_Float16)wv;
        }
        *(uh8*)(wq + idx * 8) = *(const h8*)vals;
    }
    if (tid < 320) {
        int l = (int)tid >> 5, co = (int)tid & 31;
        float v = 0.f;
        if (l < 9 && co < COt[l]) {
            int bi = bnoff[l] + co;
            float sc = g[bi] * rsqrtf(va[bi] + EPSB);
            v = be[bi] - mu[bi] * sc;
        }
        bias[tid] = v;
    }
}

// ---------------------------------------------------------------------------
// pad_x: fill the skip buffer bufS (NHWC, 32 fp16 ch/px, 130x130) for a chunk:
// channels 12..21 = x (fp16), everything else (incl. borders) = 0.
// Conv layers later overwrite only ch 0..11 interior, so x + zero-padding
// persist; dense-skip concat becomes "read bufS with 22 real channels".
// ---------------------------------------------------------------------------
__global__ void pad_x(const float* __restrict__ x, _Float16* __restrict__ bufS, int b0)
{
    int sl = blockIdx.x >> 3, part = blockIdx.x & 7;
    int gb = b0 + sl;
    const float* __restrict__ xs = x + (long)gb * 10 * HW;
    _Float16* __restrict__ d = bufS + (long)sl * PXS * 32;
    for (int p = part * 256 + threadIdx.x; p < PXS; p += 2048) {
        int r = p / W2, cc = p - r * W2;
        __attribute__((aligned(16))) _Float16 px[32];
#pragma unroll
        for (int i = 0; i < 32; ++i) px[i] = (_Float16)0.f;
        if (r >= 1 && r <= 128 && cc >= 1 && cc <= 128) {
            int so = (r - 1) * 128 + (cc - 1);
#pragma unroll
            for (int c = 0; c < 10; ++c)
                px[12 + c] = (_Float16)xs[c * HW + so];
        }
        _Float16* dp = d + (long)p * 32;
        *(uh8*)(dp)      = *(const h8*)(px);
        *(uh8*)(dp + 8)  = *(const h8*)(px + 8);
        *(uh8*)(dp + 16) = *(const h8*)(px + 16);
        *(uh8*)(dp + 24) = *(const h8*)(px + 24);
    }
}

// ---- zero the 1-px spatial borders of the two ping-pong buffers (64B/px).
// Runs ONCE: conv3 stores interior-only, so borders are never re-dirtied.
__global__ void zero_b(_Float16* __restrict__ P, _Float16* __restrict__ Q)
{
    int sl = blockIdx.x;
    _Float16* pP = P + (long)sl * PXS * 32;
    _Float16* pQ = Q + (long)sl * PXS * 32;
    h8 z = {};
    for (int j = threadIdx.x; j < 516; j += 256) {
        int p;
        if      (j < 130) p = j;
        else if (j < 260) p = 129 * W2 + (j - 130);
        else { int k = j - 260; p = (1 + (k >> 1)) * W2 + ((k & 1) ? 129 : 0); }
#pragma unroll
        for (int q = 0; q < 4; ++q) {
            *(uh8*)(pP + (long)p * 32 + q * 8) = z;
            *(uh8*)(pQ + (long)p * 32 + q * 8) = z;
        }
    }
}

// ---------------------------------------------------------------------------
// conv3: 3x3 per-sample conv as 9 shift-GEMMs on v_mfma_f32_32x32x16_f16.
// Wave tile = 4 output rows x 32 px. Group-major over (kc,ks):
//   load 6-row B window bf[6] (taps share rows vertically), then for kr=0..2:
//   load ONE A-frag, 4 independent MFMAs acc[tt] += A * bf[kr+tt].
// All buffers are uniform 64B/px NHWC (32 fp16). KST=1 layers read only
// bytes [CHOFF, CHOFF+32) (ch subset); weights are zero-padded to match.
// 1D grid nb*32 with XCD swizzle (a sample's 32 blocks share one XCD L2).
// WMODE: 0 = write all 32 ch (24-ch layers; ch24-31 get exact 0 via zero
//        weights + zero bias), 1 = write ch0-11 only (into bufS: must not
//        clobber x at ch12-21), 2 = write ch0-15 only (16-ch layers; upper
//        channels of the target are never read by the next KST=1 layer).
// ---------------------------------------------------------------------------
template<int CHOFF, int KST, int WMODE>
__global__ __launch_bounds__(256, 3)
void conv3(const _Float16* __restrict__ in, _Float16* __restrict__ out,
           const _Float16* __restrict__ wq, int loff,
           const float* __restrict__ bias, int boff, int b0)
{
    const int t  = threadIdx.x;
    const int w  = t >> 6, l = t & 63;
    const int lo5 = l & 31, hi = l >> 5;

    const int nb = (int)(gridDim.x >> 5);
    int s, tile;
    if ((nb & 7) == 0) {                      // XCD-localize each sample
        int xcd = (int)(blockIdx.x & 7);
        int j   = (int)(blockIdx.x >> 3);
        s    = xcd * (nb >> 3) + (j >> 5);
        tile = j & 31;
    } else { s = (int)(blockIdx.x >> 5); tile = (int)(blockIdx.x & 31); }
    const int gb = b0 + s;
    const int cb   = tile & 3;
    const int y0   = (tile >> 2) * 16 + w * 4;   // interior row base 0..124
    const int xpix = cb * 32 + lo5;              // interior col 0..127

    const _Float16* wl = wq + (long)gb * WQH + loff + (long)l * 8;

    // bias chunks: chunk q covers co = 8q + 4*hi + 0..3
    f4 bv[4];
#pragma unroll
    for (int q = 0; q < 4; ++q) bv[q] = *(const uf4*)(bias + boff + hi * 4 + q * 8);

    // 6 input row pointers (padded rows y0 .. y0+5)
    const char* ibb = (const char*)in + (long)s * PXS * 64
                    + (long)xpix * 64 + CHOFF + hi * 16;
    const char* rp[6];
#pragma unroll
    for (int r = 0; r < 6; ++r) rp[r] = ibb + (long)(y0 + r) * W2 * 64;

    f16v acc[4];
    {
        f16v z = {};
#pragma unroll
        for (int i = 0; i < 4; ++i) acc[i] = z;
    }

#pragma unroll
    for (int g = 0; g < 3 * KST; ++g) {
        const int kc = g / KST, ks = g - kc * KST;
        h8 bf[6];
#pragma unroll
        for (int r = 0; r < 6; ++r)
            bf[r] = *(const uh8*)(rp[r] + kc * 64 + ks * 32);
#pragma unroll
        for (int kr = 0; kr < 3; ++kr) {
            h8 af = *(const uh8*)(wl + ((kr * 3 + kc) * KST + ks) * 512);
#pragma unroll
            for (int tt = 0; tt < 4; ++tt)
                acc[tt] = __builtin_amdgcn_mfma_f32_32x32x16_f16(af, bf[kr + tt], acc[tt], 0, 0, 0);
        }
    }

    // epilogue: bias + ReLU + fp16 store (NHWC, 64B/px)
    _Float16* ob = out + (long)s * PXS * 32;
#pragma unroll
    for (int tt = 0; tt < 4; ++tt) {
        int y = y0 + tt;
        _Float16* op = ob + ((long)(y + 1) * W2 + (xpix + 1)) * 32;
        constexpr int QN = (WMODE == 0) ? 4 : 2;
#pragma unroll
        for (int q = 0; q < QN; ++q) {
            if (WMODE == 1 && q == 1 && hi) continue;   // co 12..15: keep x ch
            float v0 = fmaxf(acc[tt][4 * q + 0] + bv[q][0], 0.f);
            float v1 = fmaxf(acc[tt][4 * q + 1] + bv[q][1], 0.f);
            float v2 = fmaxf(acc[tt][4 * q + 2] + bv[q][2], 0.f);
            float v3 = fmaxf(acc[tt][4 * q + 3] + bv[q][3], 0.f);
            h4 hv = { (_Float16)v0, (_Float16)v1, (_Float16)v2, (_Float16)v3 };
            *(uh4*)(op + 8 * q + 4 * hi) = hv;
        }
    }
}

// ---- final 1x1 conv (CIN=22 in bufS, CO=11), fp32 NCHW output, no BN/ReLU.
__global__ __launch_bounds__(256, 2)
void conv1(const _Float16* __restrict__ in, float* __restrict__ outF,
           const _Float16* __restrict__ wq, int loff, int b0)
{
    const int s = blockIdx.y, gb = b0 + s;
    const int t = threadIdx.x, w = t >> 6, l = t & 63;
    const int lo5 = l & 31, hi = l >> 5;
    const int cb = blockIdx.x & 3;
    const int y00 = (blockIdx.x >> 2) * 32 + w * 8;
    const int xpix = cb * 32 + lo5;

    const _Float16* wl = wq + (long)gb * WQH + loff + (long)l * 8;
    h8 a0 = *(const uh8*)(wl);
    h8 a1 = *(const uh8*)(wl + 512);
    const _Float16* ib = in + (long)s * PXS * 32;

#pragma unroll 1
    for (int tt = 0; tt < 8; ++tt) {
        int y = y00 + tt;
        const _Float16* bp = ib + ((long)(y + 1) * W2 + xpix + 1) * 32 + hi * 8;
        h8 bA = *(const uh8*)(bp);
        h8 bB = *(const uh8*)(bp + 16);
        f16v acc = {};
        acc = __builtin_amdgcn_mfma_f32_32x32x16_f16(a0, bA, acc, 0, 0, 0);
        acc = __builtin_amdgcn_mfma_f32_32x32x16_f16(a1, bB, acc, 0, 0, 0);
        long px = (long)y * 128 + xpix;
#pragma unroll
        for (int r = 0; r < 16; ++r) {
            int co = (r & 3) + 8 * (r >> 2) + 4 * hi;
            if (co < 11) outF[((long)gb * 11 + co) * HW + px] = acc[r];
        }
    }
}

extern "C" void kernel_launch(void* const* d_in, const int* in_sizes, int n_in,
                              void* d_out, int out_size, void* d_ws, size_t ws_size,
                              hipStream_t stream)
{
    const float *x = (const float*)d_in[0], *w1 = (const float*)d_in[1],
                *w2 = (const float*)d_in[2], *w3 = (const float*)d_in[3],
                *w4 = (const float*)d_in[4], *g  = (const float*)d_in[5],
                *be = (const float*)d_in[6], *mu = (const float*)d_in[7],
                *va = (const float*)d_in[8];
    if (n_in == 9) {   // identify by size signature (fallback: dict order)
        const float* big801[2] = {nullptr, nullptr}; int n801 = 0;
        const float* bn156[4]  = {nullptr, nullptr, nullptr, nullptr}; int n156 = 0;
        const float *fx = nullptr, *fw1 = nullptr, *fw4 = nullptr;
        for (int i = 0; i < 9; ++i) {
            int sz = in_sizes[i];
            if      (sz == 10485760) fx  = (const float*)d_in[i];
            else if (sz ==   235008) fw1 = (const float*)d_in[i];
            else if (sz ==   801792) { if (n801 < 2) big801[n801++] = (const float*)d_in[i]; }
            else if (sz ==    15488) fw4 = (const float*)d_in[i];
            else if (sz ==      156) { if (n156 < 4) bn156[n156++] = (const float*)d_in[i]; }
        }
        if (fx && fw1 && fw4 && n801 == 2 && n156 == 4) {
            x = fx; w1 = fw1; w2 = big801[0]; w3 = big801[1]; w4 = fw4;
            g = bn156[0]; be = bn156[1]; mu = bn156[2]; va = bn156[3];
        }
    }
    float* out = (float*)d_out;

    // ws: [wq fp16 8.98MB][bias 2KB][bufS | P | Q], each 64B/px NHWC.
    // chunk=64 fits: 9MB + 64 * 3 * 1.08MB = 217MB < 256MiB ws (and ~L3).
    const size_t wqB   = (size_t)NB * WQH * 2;
    const size_t biasB = 2048;
    const size_t hdr   = wqB + biasB;
    const size_t perSlot = (size_t)PXS * 192;   // 3 buffers x 64B/px
    size_t avail = ws_size > hdr ? ws_size - hdr : 0;
    int chunk = (int)(avail / perSlot);
    if (chunk > NB) chunk = NB;
    if (chunk < 1)  chunk = 1;

    _Float16* wq   = (_Float16*)d_ws;
    float*    bias = (float*)((char*)d_ws + wqB);
    _Float16* bufS = (_Float16*)((char*)d_ws + hdr);
    _Float16* P    = bufS + (size_t)chunk * PXS * 32;
    _Float16* Q    = P    + (size_t)chunk * PXS * 32;

    prep_w<<<2048, 256, 0, stream>>>(w1, w2, w3, w4, g, be, mu, va, wq, bias);
    zero_b<<<chunk, 256, 0, stream>>>(P, Q);

    for (int b0 = 0; b0 < NB; b0 += chunk) {
        int nb = (NB - b0 < chunk) ? (NB - b0) : chunk;
        pad_x<<<nb * 8, 256, 0, stream>>>(x, bufS, b0);
        dim3 g1(16, nb);
        int gc = nb * 32;
        // weight frag-offsets (halves) = FO[]*8; bias offsets l*32
        conv3<24,1,2><<<gc,256,0,stream>>>(bufS, P, wq,     0, bias,   0, b0); // L0 10->12 (x @ch12)
        conv3< 0,1,2><<<gc,256,0,stream>>>(P, Q,    wq,  4608, bias,  32, b0); // L1 12->12
        conv3< 0,1,1><<<gc,256,0,stream>>>(Q, bufS, wq,  9216, bias,  64, b0); // L2 12->12 -> skip ch0-11
        conv3< 0,2,0><<<gc,256,0,stream>>>(bufS, P, wq, 13824, bias,  96, b0); // L3 22->24
        conv3< 0,2,0><<<gc,256,0,stream>>>(P, Q,    wq, 23040, bias, 128, b0); // L4 24->24
        conv3< 0,2,1><<<gc,256,0,stream>>>(Q, bufS, wq, 32256, bias, 160, b0); // L5 24->12 -> skip
        conv3< 0,2,0><<<gc,256,0,stream>>>(bufS, P, wq, 41472, bias, 192, b0); // L6 22->24
        conv3< 0,2,0><<<gc,256,0,stream>>>(P, Q,    wq, 50688, bias, 224, b0); // L7 24->24
        conv3< 0,2,1><<<gc,256,0,stream>>>(Q, bufS, wq, 59904, bias, 256, b0); // L8 24->12 -> skip
        conv1<<<g1,256,0,stream>>>(bufS, out, wq, 69120, b0);                  // L9 1x1 22->11
    }
}

// Round 4
// 537.842 us; speedup vs baseline: 1.1621x; 1.1621x over previous
//
#include <hip/hip_runtime.h>
#include <stdint.h>

#define HW    16384
#define NB    64
#define W2    130           // padded spatial dim (1-px halo each side)
#define PXS   (W2*W2)       // 16900 pixels per padded plane
#define WQH   70144         // fp16 weight halves per sample (frag-ordered)
#define EPSB  1e-5f
#define PXB   48            // LDS bytes per pixel (24 fp16 ch)
#define PROWB (38*PXB)      // LDS bytes per plane row (1824)
#define PLH   34656         // halves per LDS plane (38*38*24)

typedef _Float16 h8  __attribute__((ext_vector_type(8)));
typedef _Float16 h4  __attribute__((ext_vector_type(4)));
typedef float    f16v __attribute__((ext_vector_type(16)));
typedef float    f4  __attribute__((ext_vector_type(4)));
typedef h8 uh8 __attribute__((aligned(4)));
typedef h4 uh4 __attribute__((aligned(4)));
typedef f4 uf4 __attribute__((aligned(4)));

// ---------------------------------------------------------------------------
// prep_w: gather per-sample hypernet weights, fold BN scale, convert fp16,
// and write in EXACT mfma_32x32x16_f16 A-fragment order:
//   per layer, frame f = (tap*KST + kstep); within frame, lane(0..63) holds
//   8 halves: w[co = lane&31][c = kstep*16 + (lane>>5)*8 + e]  (0-padded).
// Frames/layer: L0-2: 9, L3-8: 18, L9(1x1): 2.
// Also emits fp32 bias[l*32+co] = beta - mu*scale (0 for padded co / L9).
// ---------------------------------------------------------------------------
__global__ void prep_w(const float* __restrict__ w1, const float* __restrict__ w2,
                       const float* __restrict__ w3, const float* __restrict__ w4,
                       const float* __restrict__ g,  const float* __restrict__ be,
                       const float* __restrict__ mu, const float* __restrict__ va,
                       _Float16* __restrict__ wq, float* __restrict__ bias)
{
    const int FO[11]   = {0,576,1152,1728,2880,4032,5184,6336,7488,8640,8768};
    const int start[10]= {0,1080,2376,3672,8424,13608,16200,20952,26136,28728};
    const int COt[10]  = {12,12,12,24,24,12,24,24,12,11};
    const int CIt[10]  = {10,12,12,22,24,24,22,24,24,22};
    const int bnoff[10]= {0,12,24,36,60,84,96,120,144,0};
    const int KST[10]  = {1,1,1,2,2,2,2,2,2,2};

    long tid = (long)blockIdx.x * 256 + threadIdx.x;
    long total = (long)NB * 8768, stride = (long)gridDim.x * 256;
    for (long idx = tid; idx < total; idx += stride) {
        int b = (int)(idx / 8768), i = (int)(idx - (long)b * 8768);
        int l = 9; while (i < FO[l]) --l;
        int j = i - FO[l];
        int f = j >> 6, lane = j & 63;
        int ks = (KST[l] == 2) ? (f & 1) : 0;
        int s  = (KST[l] == 2) ? (f >> 1) : f;      // 3x3 tap index (0 for L9)
        int co = lane & 31, hi = lane >> 5;
        int CO = COt[l], CI = CIt[l];
        float scale = 1.f;
        if (l < 9 && co < CO) {
            int bi = bnoff[l] + co;
            scale = g[bi] * rsqrtf(va[bi] + EPSB);
        }
        int c0 = ks * 16 + hi * 8;
        __attribute__((aligned(16))) _Float16 vals[8];
#pragma unroll
        for (int e = 0; e < 8; ++e) {
            int c = c0 + e; float wv = 0.f;
            if (co < CO && c < CI) {
                int p = (l < 9) ? start[l] + (co * CI + c) * 9 + s
                                : start[9] + co * CI + c;
                const float* src; long si;
                if      (p <  3672) { src = w1; si = (long)b *  3672 + p; }
                else if (p < 16200) { src = w2; si = (long)b * 12528 + (p -  3672); }
                else if (p < 28728) { src = w3; si = (long)b * 12528 + (p - 16200); }
                else                { src = w4; si = (long)b *   242 + (p - 28728); }
                wv = src[si] * scale;
            }
            vals[e] = (_Float16)wv;
        }
        *(uh8*)(wq + idx * 8) = *(const h8*)vals;
    }
    if (tid < 320) {
        int l = (int)tid >> 5, co = (int)tid & 31;
        float v = 0.f;
        if (l < 9 && co < COt[l]) {
            int bi = bnoff[l] + co;
            float sc = g[bi] * rsqrtf(va[bi] + EPSB);
            v = be[bi] - mu[bi] * sc;
        }
        bias[tid] = v;
    }
}

// ---------------------------------------------------------------------------
// pad_x: init both NHWC 32-ch fp16 buffers for a chunk.
//   bufA: ch0-9 = x, ch10-11 = 0, ch12-21 = x, ch22-31 = 0  (stage1 input:
//         L0 reads ci0-9 = x at ch0-9; extra x copy at 12-21 hits zero weights)
//   bufB: ch12-21 = x, rest 0                                (skip-concat copy)
// Borders and all unused channels zeroed (downstream reads must never see
// poison: conv1 reads ch24-31, stages read ch22-23).
// ---------------------------------------------------------------------------
__global__ void pad_x(const float* __restrict__ x, _Float16* __restrict__ bufA,
                      _Float16* __restrict__ bufB, int b0)
{
    int sl = blockIdx.x >> 3, part = blockIdx.x & 7;
    int gb = b0 + sl;
    const float* __restrict__ xs = x + (long)gb * 10 * HW;
    _Float16* __restrict__ dA = bufA + (long)sl * PXS * 32;
    _Float16* __restrict__ dB = bufB + (long)sl * PXS * 32;
    for (int p = part * 256 + threadIdx.x; p < PXS; p += 2048) {
        int r = p / W2, cc = p - r * W2;
        __attribute__((aligned(16))) _Float16 pxA[32], pxB[32];
#pragma unroll
        for (int i = 0; i < 32; ++i) { pxA[i] = (_Float16)0.f; pxB[i] = (_Float16)0.f; }
        if (r >= 1 && r <= 128 && cc >= 1 && cc <= 128) {
            int so = (r - 1) * 128 + (cc - 1);
#pragma unroll
            for (int c = 0; c < 10; ++c) {
                _Float16 xv = (_Float16)xs[c * HW + so];
                pxA[c] = xv; pxA[12 + c] = xv; pxB[12 + c] = xv;
            }
        }
        _Float16* ap = dA + (long)p * 32;
        _Float16* bp = dB + (long)p * 32;
#pragma unroll
        for (int q = 0; q < 4; ++q) {
            *(uh8*)(ap + q * 8) = *(const h8*)(pxA + q * 8);
            *(uh8*)(bp + q * 8) = *(const h8*)(pxB + q * 8);
        }
    }
}

// ---------------------------------------------------------------------------
// lconv: one 3x3 conv layer, LDS plane -> LDS plane, region-shrinking.
// Plane layout: 38x38 px * 48B (24 fp16 ch); px stride 48B gives granule
// stride 3 (coprime with 8) -> no extra bank conflicts on ds_read_b128.
// Output region: rows [rowStart, rowStart+nRows) x cols [colStart, +width),
// computed as row-groups of 4 x col-blocks of 32 px (cb1 overlaps, stores
// only its rightmost 64-width lanes). Values outside global interior
// (padded coords 1..128) are stored as ZERO = the reference's conv padding.
// B frag (ks,hi): plane px bytes [ks*32 + hi*16, +16) = ci ks*16+hi*8..+8;
// ks=1,hi=1 (ci 24-31) is implicit zero. Matches prep_w A-frag order.
// ---------------------------------------------------------------------------
template<int KST>
__device__ __forceinline__ void lconv(const char* pin, char* pout,
    const _Float16* wl, const float* __restrict__ bias, int boff,
    int rowStart, int nRows, int colStart, int width,
    int oy0, int ox0, int w, int lo5, int hi)
{
    constexpr int FR = 9 * KST;
    h8 afr[FR];
#pragma unroll
    for (int f = 0; f < FR; ++f) afr[f] = *(const uh8*)(wl + (long)f * 512);
    f4 bv[4];
#pragma unroll
    for (int q = 0; q < 4; ++q) bv[q] = *(const uf4*)(bias + boff + hi * 4 + q * 8);
    constexpr int qmax = (KST == 1) ? 2 : 3;   // store ch0-15 / ch0-23

    const int ncb = (width > 32) ? 2 : 1;
    const int nrg = (nRows + 3) >> 2;
    const int nu  = nrg * ncb;
#pragma unroll 1
    for (int u = w; u < nu; u += 4) {
        int rg, cb;
        if (ncb == 2) { rg = u >> 1; cb = u & 1; } else { rg = u; cb = 0; }
        const int r0   = rowStart + rg * 4;
        const int cs   = cb ? (colStart + width - 32) : colStart;
        const int cmin = cb ? (64 - width) : 0;
        const char* bin = pin + (long)(cs - 1 + lo5) * PXB + hi * 16;

        f16v acc[4];
        { f16v z = {}; acc[0] = z; acc[1] = z; acc[2] = z; acc[3] = z; }

#pragma unroll
        for (int kc = 0; kc < 3; ++kc)
#pragma unroll
        for (int ks = 0; ks < KST; ++ks) {
            h8 bf[6];
#pragma unroll
            for (int j = 0; j < 6; ++j) {
                int rr = r0 - 1 + j; rr = (rr > 37) ? 37 : rr;  // clamp: masked rows only
                h8 v = {};
                if (!(ks & hi))
                    v = *(const uh8*)(bin + (long)rr * PROWB + kc * PXB + ks * 32);
                bf[j] = v;
            }
#pragma unroll
            for (int kr = 0; kr < 3; ++kr) {
                h8 af = afr[(kr * 3 + kc) * KST + ks];
#pragma unroll
                for (int tt = 0; tt < 4; ++tt)
                    acc[tt] = __builtin_amdgcn_mfma_f32_32x32x16_f16(af, bf[kr + tt], acc[tt], 0, 0, 0);
            }
        }

        const bool cok = (lo5 >= cmin);
        const int  pc  = cs + lo5;
        const int  gx  = ox0 - 3 + pc;
        const bool xin = (unsigned)(gx - 1) < 128u;
#pragma unroll
        for (int tt = 0; tt < 4; ++tt) {
            int pr = r0 + tt;
            if (pr >= rowStart + nRows) continue;
            int gy = oy0 - 3 + pr;
            bool ok = xin && ((unsigned)(gy - 1) < 128u);
            char* po = pout + ((long)pr * 38 + pc) * PXB + hi * 8;
            if (cok) {
#pragma unroll
                for (int q = 0; q < qmax; ++q) {
                    float v0 = ok ? fmaxf(acc[tt][4*q+0] + bv[q][0], 0.f) : 0.f;
                    float v1 = ok ? fmaxf(acc[tt][4*q+1] + bv[q][1], 0.f) : 0.f;
                    float v2 = ok ? fmaxf(acc[tt][4*q+2] + bv[q][2], 0.f) : 0.f;
                    float v3 = ok ? fmaxf(acc[tt][4*q+3] + bv[q][3], 0.f) : 0.f;
                    h4 hv = { (_Float16)v0, (_Float16)v1, (_Float16)v2, (_Float16)v3 };
                    *(uh4*)(po + q * 16) = hv;
                }
            }
        }
    }
}

// ---------------------------------------------------------------------------
// stage3: fused 3-conv stage. Per block: one 32x32 output tile of one sample.
//  1) stage 38x38 px x ch0-23 from global NHWC (64B/px) into LDS plane S
//     (load-all-then-write-all: 17 global 16B loads/thread -> deep MLP);
//     out-of-buffer px staged as zero (virtual 3-px halo).
//  2) conv A: S->T (36x36), conv B: T->S (34x34), conv C: S->T (32x32),
//     barriers between; pad positions forced to zero (reference semantics).
//  3) write T's 32x32 interior, ch0-11 only, to global out (skip-concat:
//     x at ch12-21 of out buffer is preserved).
// LDS 138.6 KB -> 1 block/CU; weights preloaded to registers (VGPR-free).
// ---------------------------------------------------------------------------
template<int KST>
__global__ __launch_bounds__(256, 1)
void stage3(const _Float16* __restrict__ in, _Float16* __restrict__ out,
            const _Float16* __restrict__ wq, int loff0,
            const float* __restrict__ bias, int boff0, int b0)
{
    __shared__ _Float16 lds[2][PLH];
    const int t = threadIdx.x, w = t >> 6, l = t & 63;
    const int lo5 = l & 31, hi = l >> 5;

    const int nbb = (int)(gridDim.x >> 4);
    int s, tile;
    if ((nbb & 7) == 0) {                       // XCD-localize each sample
        int xcd = (int)(blockIdx.x & 7), j = (int)(blockIdx.x >> 3);
        s = xcd * (nbb >> 3) + (j >> 4); tile = j & 15;
    } else { s = (int)(blockIdx.x >> 4); tile = (int)(blockIdx.x & 15); }
    const int gb  = b0 + s;
    const int oy0 = 1 + (tile >> 2) * 32;       // padded-coord tile origin
    const int ox0 = 1 + (tile & 3) * 32;

    // ---- 1) stage input window: 4332 granules of 16B (38 rows x 114)
    {
        const char* src = (const char*)(in + (long)s * PXS * 32);
        char* dst = (char*)&lds[0][0];
        h8 stg[17];
#pragma unroll
        for (int k = 0; k < 17; ++k) {
            int idx = k * 256 + t;
            int r = idx / 114, g2 = idx - r * 114;
            int p = g2 / 3,   c  = g2 - p * 3;
            int gy = oy0 - 3 + r, gx = ox0 - 3 + p;
            h8 v = {};
            if (idx < 4332 && (unsigned)gy < 130u && (unsigned)gx < 130u)
                v = *(const uh8*)(src + ((long)gy * W2 + gx) * 64 + c * 16);
            stg[k] = v;
        }
#pragma unroll
        for (int k = 0; k < 17; ++k) {
            int idx = k * 256 + t;
            if (idx < 4332) *(uh8*)(dst + (long)idx * 16) = stg[k];
        }
    }
    __syncthreads();

    // ---- 2) three convs (regions 36 -> 34 -> 32)
    const _Float16* wl = wq + (long)gb * WQH + loff0 + (long)l * 8;
    constexpr int LSTEP = 9 * KST * 512;
    lconv<KST>((const char*)lds[0], (char*)lds[1], wl,             bias, boff0,      1, 36, 1, 36, oy0, ox0, w, lo5, hi);
    __syncthreads();
    lconv<KST>((const char*)lds[1], (char*)lds[0], wl + LSTEP,     bias, boff0 + 32, 2, 34, 2, 34, oy0, ox0, w, lo5, hi);
    __syncthreads();
    lconv<KST>((const char*)lds[0], (char*)lds[1], wl + 2 * LSTEP, bias, boff0 + 64, 3, 32, 3, 32, oy0, ox0, w, lo5, hi);
    __syncthreads();

    // ---- 3) write ch0-11 of the 32x32 interior to global
    {
        _Float16* db = out + (long)s * PXS * 32;
        const char* T = (const char*)&lds[1][0];
#pragma unroll
        for (int k = 0; k < 4; ++k) {
            int px = k * 256 + t;
            int pr = 3 + (px >> 5), pc = 3 + (px & 31);
            int gy = oy0 + (px >> 5), gx = ox0 + (px & 31);
            const char* sp = T + ((long)pr * 38 + pc) * PXB;
            h8 v0 = *(const uh8*)sp;
            h4 v1 = *(const uh4*)(sp + 16);
            _Float16* dp = db + ((long)gy * W2 + gx) * 32;
            *(uh8*)dp = v0;
            *(uh4*)(dp + 8) = v1;
        }
    }
}

// ---- final 1x1 conv (CIN=22 in bufB, CO=11), fp32 NCHW output, no BN/ReLU.
__global__ __launch_bounds__(256, 2)
void conv1(const _Float16* __restrict__ in, float* __restrict__ outF,
           const _Float16* __restrict__ wq, int loff, int b0)
{
    const int s = blockIdx.y, gb = b0 + s;
    const int t = threadIdx.x, w = t >> 6, l = t & 63;
    const int lo5 = l & 31, hi = l >> 5;
    const int cb = blockIdx.x & 3;
    const int y00 = (blockIdx.x >> 2) * 32 + w * 8;
    const int xpix = cb * 32 + lo5;

    const _Float16* wl = wq + (long)gb * WQH + loff + (long)l * 8;
    h8 a0 = *(const uh8*)(wl);
    h8 a1 = *(const uh8*)(wl + 512);
    const _Float16* ib = in + (long)s * PXS * 32;

#pragma unroll 1
    for (int tt = 0; tt < 8; ++tt) {
        int y = y00 + tt;
        const _Float16* bp = ib + ((long)(y + 1) * W2 + xpix + 1) * 32 + hi * 8;
        h8 bA = *(const uh8*)(bp);
        h8 bB = *(const uh8*)(bp + 16);
        f16v acc = {};
        acc = __builtin_amdgcn_mfma_f32_32x32x16_f16(a0, bA, acc, 0, 0, 0);
        acc = __builtin_amdgcn_mfma_f32_32x32x16_f16(a1, bB, acc, 0, 0, 0);
        long px = (long)y * 128 + xpix;
#pragma unroll
        for (int r = 0; r < 16; ++r) {
            int co = (r & 3) + 8 * (r >> 2) + 4 * hi;
            if (co < 11) outF[((long)gb * 11 + co) * HW + px] = acc[r];
        }
    }
}

extern "C" void kernel_launch(void* const* d_in, const int* in_sizes, int n_in,
                              void* d_out, int out_size, void* d_ws, size_t ws_size,
                              hipStream_t stream)
{
    const float *x = (const float*)d_in[0], *w1 = (const float*)d_in[1],
                *w2 = (const float*)d_in[2], *w3 = (const float*)d_in[3],
                *w4 = (const float*)d_in[4], *g  = (const float*)d_in[5],
                *be = (const float*)d_in[6], *mu = (const float*)d_in[7],
                *va = (const float*)d_in[8];
    if (n_in == 9) {   // identify by size signature (fallback: dict order)
        const float* big801[2] = {nullptr, nullptr}; int n801 = 0;
        const float* bn156[4]  = {nullptr, nullptr, nullptr, nullptr}; int n156 = 0;
        const float *fx = nullptr, *fw1 = nullptr, *fw4 = nullptr;
        for (int i = 0; i < 9; ++i) {
            int sz = in_sizes[i];
            if      (sz == 10485760) fx  = (const float*)d_in[i];
            else if (sz ==   235008) fw1 = (const float*)d_in[i];
            else if (sz ==   801792) { if (n801 < 2) big801[n801++] = (const float*)d_in[i]; }
            else if (sz ==    15488) fw4 = (const float*)d_in[i];
            else if (sz ==      156) { if (n156 < 4) bn156[n156++] = (const float*)d_in[i]; }
        }
        if (fx && fw1 && fw4 && n801 == 2 && n156 == 4) {
            x = fx; w1 = fw1; w2 = big801[0]; w3 = big801[1]; w4 = fw4;
            g = bn156[0]; be = bn156[1]; mu = bn156[2]; va = bn156[3];
        }
    }
    float* out = (float*)d_out;

    // ws: [wq fp16 8.98MB][bias 2KB][bufA | bufB], each 64B/px NHWC padded.
    // chunk=64 needs 9MB + 2*64*1.08MB = 147MB.
    const size_t wqB   = (size_t)NB * WQH * 2;
    const size_t biasB = 2048;
    const size_t hdr   = wqB + biasB;
    const size_t perSlot = (size_t)PXS * 128;   // 2 buffers x 64B/px
    size_t avail = ws_size > hdr ? ws_size - hdr : 0;
    int chunk = (int)(avail / perSlot);
    if (chunk > NB) chunk = NB;
    if (chunk < 1)  chunk = 1;

    _Float16* wq   = (_Float16*)d_ws;
    float*    bias = (float*)((char*)d_ws + wqB);
    _Float16* bufA = (_Float16*)((char*)d_ws + hdr);
    _Float16* bufB = bufA + (size_t)chunk * PXS * 32;

    prep_w<<<2048, 256, 0, stream>>>(w1, w2, w3, w4, g, be, mu, va, wq, bias);

    for (int b0 = 0; b0 < NB; b0 += chunk) {
        int nb = (NB - b0 < chunk) ? (NB - b0) : chunk;
        pad_x<<<nb * 8, 256, 0, stream>>>(x, bufA, bufB, b0);
        int gc = nb * 16;
        dim3 g1(16, nb);
        // stage1: L0-L2 (x @ bufA ch0-9) -> bufB ch0-11
        stage3<1><<<gc, 256, 0, stream>>>(bufA, bufB, wq,     0, bias,   0, b0);
        // stage2: L3-L5 (bufB: prev@0-11 + x@12-21) -> bufA ch0-11
        stage3<2><<<gc, 256, 0, stream>>>(bufB, bufA, wq, 13824, bias,  96, b0);
        // stage3: L6-L8 -> bufB ch0-11
        stage3<2><<<gc, 256, 0, stream>>>(bufA, bufB, wq, 41472, bias, 192, b0);
        // L9: 1x1, 22ch -> 11ch fp32
        conv1<<<g1, 256, 0, stream>>>(bufB, out, wq, 69120, b0);
    }
}

// Round 5
// 475.887 us; speedup vs baseline: 1.3134x; 1.1302x over previous
//
#include <hip/hip_runtime.h>
#include <stdint.h>

#define HW    16384
#define NB    64
#define W2    130           // padded spatial dim (1-px halo each side)
#define PXS   (W2*W2)       // 16900 pixels per padded plane
#define WQH   70144         // fp16 weight halves per sample (frag-ordered)
#define EPSB  1e-5f
#define PXB   48            // LDS bytes per pixel (24 fp16 ch)
#define PROWB (38*PXB)      // LDS bytes per plane row (1824)
#define PLH   34656         // halves per LDS plane (38*38*24)
#define NTH   768           // stage3 threads (12 waves -> 3 waves/SIMD)
#define NWV   12

typedef _Float16 h8  __attribute__((ext_vector_type(8)));
typedef _Float16 h4  __attribute__((ext_vector_type(4)));
typedef float    f16v __attribute__((ext_vector_type(16)));
typedef float    f4  __attribute__((ext_vector_type(4)));
typedef h8 uh8 __attribute__((aligned(4)));
typedef h4 uh4 __attribute__((aligned(4)));
typedef f4 uf4 __attribute__((aligned(4)));

// ---------------------------------------------------------------------------
// prep_w: gather per-sample hypernet weights, fold BN scale, convert fp16,
// and write in EXACT mfma_32x32x16_f16 A-fragment order:
//   per layer, frame f = (tap*KST + kstep); within frame, lane(0..63) holds
//   8 halves: w[co = lane&31][c = kstep*16 + (lane>>5)*8 + e]  (0-padded).
// Frames/layer: L0-2: 9, L3-8: 18, L9(1x1): 2.
// Also emits fp32 bias[l*32+co] = beta - mu*scale (0 for padded co / L9).
// ---------------------------------------------------------------------------
__global__ void prep_w(const float* __restrict__ w1, const float* __restrict__ w2,
                       const float* __restrict__ w3, const float* __restrict__ w4,
                       const float* __restrict__ g,  const float* __restrict__ be,
                       const float* __restrict__ mu, const float* __restrict__ va,
                       _Float16* __restrict__ wq, float* __restrict__ bias)
{
    const int FO[11]   = {0,576,1152,1728,2880,4032,5184,6336,7488,8640,8768};
    const int start[10]= {0,1080,2376,3672,8424,13608,16200,20952,26136,28728};
    const int COt[10]  = {12,12,12,24,24,12,24,24,12,11};
    const int CIt[10]  = {10,12,12,22,24,24,22,24,24,22};
    const int bnoff[10]= {0,12,24,36,60,84,96,120,144,0};
    const int KST[10]  = {1,1,1,2,2,2,2,2,2,2};

    long tid = (long)blockIdx.x * 256 + threadIdx.x;
    long total = (long)NB * 8768, stride = (long)gridDim.x * 256;
    for (long idx = tid; idx < total; idx += stride) {
        int b = (int)(idx / 8768), i = (int)(idx - (long)b * 8768);
        int l = 9; while (i < FO[l]) --l;
        int j = i - FO[l];
        int f = j >> 6, lane = j & 63;
        int ks = (KST[l] == 2) ? (f & 1) : 0;
        int s  = (KST[l] == 2) ? (f >> 1) : f;      // 3x3 tap index (0 for L9)
        int co = lane & 31, hi = lane >> 5;
        int CO = COt[l], CI = CIt[l];
        float scale = 1.f;
        if (l < 9 && co < CO) {
            int bi = bnoff[l] + co;
            scale = g[bi] * rsqrtf(va[bi] + EPSB);
        }
        int c0 = ks * 16 + hi * 8;
        __attribute__((aligned(16))) _Float16 vals[8];
#pragma unroll
        for (int e = 0; e < 8; ++e) {
            int c = c0 + e; float wv = 0.f;
            if (co < CO && c < CI) {
                int p = (l < 9) ? start[l] + (co * CI + c) * 9 + s
                                : start[9] + co * CI + c;
                const float* src; long si;
                if      (p <  3672) { src = w1; si = (long)b *  3672 + p; }
                else if (p < 16200) { src = w2; si = (long)b * 12528 + (p -  3672); }
                else if (p < 28728) { src = w3; si = (long)b * 12528 + (p - 16200); }
                else                { src = w4; si = (long)b *   242 + (p - 28728); }
                wv = src[si] * scale;
            }
            vals[e] = (_Float16)wv;
        }
        *(uh8*)(wq + idx * 8) = *(const h8*)vals;
    }
    if (tid < 320) {
        int l = (int)tid >> 5, co = (int)tid & 31;
        float v = 0.f;
        if (l < 9 && co < COt[l]) {
            int bi = bnoff[l] + co;
            float sc = g[bi] * rsqrtf(va[bi] + EPSB);
            v = be[bi] - mu[bi] * sc;
        }
        bias[tid] = v;
    }
}

// ---------------------------------------------------------------------------
// pad_x: init both NHWC 32-ch fp16 buffers for a chunk.
//   bufA: ch0-9 = x, ch10-11 = 0, ch12-21 = x, ch22-31 = 0  (stage1 input)
//   bufB: ch12-21 = x, rest 0                                (skip-concat copy)
// Borders and all unused channels zeroed.
// ---------------------------------------------------------------------------
__global__ void pad_x(const float* __restrict__ x, _Float16* __restrict__ bufA,
                      _Float16* __restrict__ bufB, int b0)
{
    int sl = blockIdx.x >> 3, part = blockIdx.x & 7;
    int gb = b0 + sl;
    const float* __restrict__ xs = x + (long)gb * 10 * HW;
    _Float16* __restrict__ dA = bufA + (long)sl * PXS * 32;
    _Float16* __restrict__ dB = bufB + (long)sl * PXS * 32;
    for (int p = part * 256 + threadIdx.x; p < PXS; p += 2048) {
        int r = p / W2, cc = p - r * W2;
        __attribute__((aligned(16))) _Float16 pxA[32], pxB[32];
#pragma unroll
        for (int i = 0; i < 32; ++i) { pxA[i] = (_Float16)0.f; pxB[i] = (_Float16)0.f; }
        if (r >= 1 && r <= 128 && cc >= 1 && cc <= 128) {
            int so = (r - 1) * 128 + (cc - 1);
#pragma unroll
            for (int c = 0; c < 10; ++c) {
                _Float16 xv = (_Float16)xs[c * HW + so];
                pxA[c] = xv; pxA[12 + c] = xv; pxB[12 + c] = xv;
            }
        }
        _Float16* ap = dA + (long)p * 32;
        _Float16* bp = dB + (long)p * 32;
#pragma unroll
        for (int q = 0; q < 4; ++q) {
            *(uh8*)(ap + q * 8) = *(const h8*)(pxA + q * 8);
            *(uh8*)(bp + q * 8) = *(const h8*)(pxB + q * 8);
        }
    }
}

// ---------------------------------------------------------------------------
// lconv: one 3x3 conv layer, LDS plane -> LDS plane, region-shrinking.
// Unit = NR output rows x 32 px col-block; units strided across 12 waves.
// NR=3 for 36/34-row layers (24 units -> exactly 2/wave), NR=4 for the
// final 32-row layer (8 units -> 1/wave for 8 of 12 waves).
// A-frag loaded per-kr from global (16B, L1-resident after first wave) to
// keep VGPR below the 12-wave residency cap (~170).
// Pad positions (outside global interior) stored as ZERO = reference's
// zero-padding between convs.
// ---------------------------------------------------------------------------
template<int KST, int NR>
__device__ __forceinline__ void lconv(const char* pin, char* pout,
    const _Float16* wl, const float* __restrict__ bias, int boff,
    int rowStart, int nRows, int colStart, int width,
    int oy0, int ox0, int w, int lo5, int hi)
{
    f4 bv[4];
#pragma unroll
    for (int q = 0; q < 4; ++q) bv[q] = *(const uf4*)(bias + boff + hi * 4 + q * 8);
    constexpr int qmax = (KST == 1) ? 2 : 3;   // store ch0-15 / ch0-23

    const int ncb = (width > 32) ? 2 : 1;
    const int nrg = (nRows + NR - 1) / NR;
    const int nu  = nrg * ncb;
#pragma unroll 1
    for (int u = w; u < nu; u += NWV) {
        int rg, cb;
        if (ncb == 2) { rg = u >> 1; cb = u & 1; } else { rg = u; cb = 0; }
        const int r0   = rowStart + rg * NR;
        const int cs   = cb ? (colStart + width - 32) : colStart;
        const int cmin = cb ? (64 - width) : 0;
        const char* bin = pin + (long)(cs - 1 + lo5) * PXB + hi * 16;

        f16v acc[NR];
        { f16v z = {};
#pragma unroll
          for (int i = 0; i < NR; ++i) acc[i] = z; }

#pragma unroll
        for (int kc = 0; kc < 3; ++kc)
#pragma unroll
        for (int ks = 0; ks < KST; ++ks) {
            h8 bf[NR + 2];
#pragma unroll
            for (int j = 0; j < NR + 2; ++j) {
                int rr = r0 - 1 + j; rr = (rr > 37) ? 37 : rr;  // clamp: masked rows only
                h8 v = {};
                if (!(ks & hi))
                    v = *(const uh8*)(bin + (long)rr * PROWB + kc * PXB + ks * 32);
                bf[j] = v;
            }
#pragma unroll
            for (int kr = 0; kr < 3; ++kr) {
                h8 af = *(const uh8*)(wl + ((kr * 3 + kc) * KST + ks) * 512);
#pragma unroll
                for (int tt = 0; tt < NR; ++tt)
                    acc[tt] = __builtin_amdgcn_mfma_f32_32x32x16_f16(af, bf[kr + tt], acc[tt], 0, 0, 0);
            }
        }

        const bool cok = (lo5 >= cmin);
        const int  pc  = cs + lo5;
        const int  gx  = ox0 - 3 + pc;
        const bool xin = (unsigned)(gx - 1) < 128u;
#pragma unroll
        for (int tt = 0; tt < NR; ++tt) {
            int pr = r0 + tt;
            if (pr >= rowStart + nRows) continue;
            int gy = oy0 - 3 + pr;
            bool ok = xin && ((unsigned)(gy - 1) < 128u);
            char* po = pout + ((long)pr * 38 + pc) * PXB + hi * 8;
            if (cok) {
#pragma unroll
                for (int q = 0; q < qmax; ++q) {
                    float v0 = ok ? fmaxf(acc[tt][4*q+0] + bv[q][0], 0.f) : 0.f;
                    float v1 = ok ? fmaxf(acc[tt][4*q+1] + bv[q][1], 0.f) : 0.f;
                    float v2 = ok ? fmaxf(acc[tt][4*q+2] + bv[q][2], 0.f) : 0.f;
                    float v3 = ok ? fmaxf(acc[tt][4*q+3] + bv[q][3], 0.f) : 0.f;
                    h4 hv = { (_Float16)v0, (_Float16)v1, (_Float16)v2, (_Float16)v3 };
                    *(uh4*)(po + q * 16) = hv;
                }
            }
        }
    }
}

// ---------------------------------------------------------------------------
// stage3: fused 3-conv stage, 768 threads (12 waves, 3/SIMD; 1 block/CU due
// to 138.75KB LDS). Per block: one 32x32 output tile of one sample.
//  1) stage 38x38 px x ch0-23 from global NHWC (64B/px) into LDS plane S.
//  2) conv A: S->T (36x36, NR=3), conv B: T->S (34x34, NR=3),
//     conv C: S->T (32x32, NR=4), barriers between.
//  3) write T's 32x32 interior, ch0-11 only, to global out (skip-concat:
//     x at ch12-21 of out buffer is preserved).
// ---------------------------------------------------------------------------
template<int KST>
__global__ __launch_bounds__(NTH)
void stage3(const _Float16* __restrict__ in, _Float16* __restrict__ out,
            const _Float16* __restrict__ wq, int loff0,
            const float* __restrict__ bias, int boff0, int b0)
{
    __shared__ _Float16 lds[2][PLH];
    const int t = threadIdx.x, w = t >> 6, l = t & 63;
    const int lo5 = l & 31, hi = l >> 5;

    const int nbb = (int)(gridDim.x >> 4);
    int s, tile;
    if ((nbb & 7) == 0) {                       // XCD-localize each sample
        int xcd = (int)(blockIdx.x & 7), j = (int)(blockIdx.x >> 3);
        s = xcd * (nbb >> 3) + (j >> 4); tile = j & 15;
    } else { s = (int)(blockIdx.x >> 4); tile = (int)(blockIdx.x & 15); }
    const int gb  = b0 + s;
    const int oy0 = 1 + (tile >> 2) * 32;       // padded-coord tile origin
    const int ox0 = 1 + (tile & 3) * 32;

    // ---- 1) stage input window: 4332 granules of 16B (38 rows x 114)
    {
        const char* src = (const char*)(in + (long)s * PXS * 32);
        char* dst = (char*)&lds[0][0];
        h8 stg[6];
#pragma unroll
        for (int k = 0; k < 6; ++k) {
            int idx = k * NTH + t;
            int r = idx / 114, g2 = idx - r * 114;
            int p = g2 / 3,   c  = g2 - p * 3;
            int gy = oy0 - 3 + r, gx = ox0 - 3 + p;
            h8 v = {};
            if (idx < 4332 && (unsigned)gy < 130u && (unsigned)gx < 130u)
                v = *(const uh8*)(src + ((long)gy * W2 + gx) * 64 + c * 16);
            stg[k] = v;
        }
#pragma unroll
        for (int k = 0; k < 6; ++k) {
            int idx = k * NTH + t;
            if (idx < 4332) *(uh8*)(dst + (long)idx * 16) = stg[k];
        }
    }
    __syncthreads();

    // ---- 2) three convs (regions 36 -> 34 -> 32)
    const _Float16* wl = wq + (long)gb * WQH + loff0 + (long)l * 8;
    constexpr int LSTEP = 9 * KST * 512;
    lconv<KST,3>((const char*)lds[0], (char*)lds[1], wl,             bias, boff0,      1, 36, 1, 36, oy0, ox0, w, lo5, hi);
    __syncthreads();
    lconv<KST,3>((const char*)lds[1], (char*)lds[0], wl + LSTEP,     bias, boff0 + 32, 2, 34, 2, 34, oy0, ox0, w, lo5, hi);
    __syncthreads();
    lconv<KST,4>((const char*)lds[0], (char*)lds[1], wl + 2 * LSTEP, bias, boff0 + 64, 3, 32, 3, 32, oy0, ox0, w, lo5, hi);
    __syncthreads();

    // ---- 3) write ch0-11 of the 32x32 interior to global
    {
        _Float16* db = out + (long)s * PXS * 32;
        const char* T = (const char*)&lds[1][0];
#pragma unroll
        for (int k = 0; k < 2; ++k) {
            int px = k * NTH + t;
            if (px < 1024) {
                int pr = 3 + (px >> 5), pc = 3 + (px & 31);
                int gy = oy0 + (px >> 5), gx = ox0 + (px & 31);
                const char* sp = T + ((long)pr * 38 + pc) * PXB;
                h8 v0 = *(const uh8*)sp;
                h4 v1 = *(const uh4*)(sp + 16);
                _Float16* dp = db + ((long)gy * W2 + gx) * 32;
                *(uh8*)dp = v0;
                *(uh4*)(dp + 8) = v1;
            }
        }
    }
}

// ---- final 1x1 conv (CIN=22 in bufB, CO=11), fp32 NCHW output, no BN/ReLU.
__global__ __launch_bounds__(256, 2)
void conv1(const _Float16* __restrict__ in, float* __restrict__ outF,
           const _Float16* __restrict__ wq, int loff, int b0)
{
    const int s = blockIdx.y, gb = b0 + s;
    const int t = threadIdx.x, w = t >> 6, l = t & 63;
    const int lo5 = l & 31, hi = l >> 5;
    const int cb = blockIdx.x & 3;
    const int y00 = (blockIdx.x >> 2) * 32 + w * 8;
    const int xpix = cb * 32 + lo5;

    const _Float16* wl = wq + (long)gb * WQH + loff + (long)l * 8;
    h8 a0 = *(const uh8*)(wl);
    h8 a1 = *(const uh8*)(wl + 512);
    const _Float16* ib = in + (long)s * PXS * 32;

#pragma unroll 1
    for (int tt = 0; tt < 8; ++tt) {
        int y = y00 + tt;
        const _Float16* bp = ib + ((long)(y + 1) * W2 + xpix + 1) * 32 + hi * 8;
        h8 bA = *(const uh8*)(bp);
        h8 bB = *(const uh8*)(bp + 16);
        f16v acc = {};
        acc = __builtin_amdgcn_mfma_f32_32x32x16_f16(a0, bA, acc, 0, 0, 0);
        acc = __builtin_amdgcn_mfma_f32_32x32x16_f16(a1, bB, acc, 0, 0, 0);
        long px = (long)y * 128 + xpix;
#pragma unroll
        for (int r = 0; r < 16; ++r) {
            int co = (r & 3) + 8 * (r >> 2) + 4 * hi;
            if (co < 11) outF[((long)gb * 11 + co) * HW + px] = acc[r];
        }
    }
}

extern "C" void kernel_launch(void* const* d_in, const int* in_sizes, int n_in,
                              void* d_out, int out_size, void* d_ws, size_t ws_size,
                              hipStream_t stream)
{
    const float *x = (const float*)d_in[0], *w1 = (const float*)d_in[1],
                *w2 = (const float*)d_in[2], *w3 = (const float*)d_in[3],
                *w4 = (const float*)d_in[4], *g  = (const float*)d_in[5],
                *be = (const float*)d_in[6], *mu = (const float*)d_in[7],
                *va = (const float*)d_in[8];
    if (n_in == 9) {   // identify by size signature (fallback: dict order)
        const float* big801[2] = {nullptr, nullptr}; int n801 = 0;
        const float* bn156[4]  = {nullptr, nullptr, nullptr, nullptr}; int n156 = 0;
        const float *fx = nullptr, *fw1 = nullptr, *fw4 = nullptr;
        for (int i = 0; i < 9; ++i) {
            int sz = in_sizes[i];
            if      (sz == 10485760) fx  = (const float*)d_in[i];
            else if (sz ==   235008) fw1 = (const float*)d_in[i];
            else if (sz ==   801792) { if (n801 < 2) big801[n801++] = (const float*)d_in[i]; }
            else if (sz ==    15488) fw4 = (const float*)d_in[i];
            else if (sz ==      156) { if (n156 < 4) bn156[n156++] = (const float*)d_in[i]; }
        }
        if (fx && fw1 && fw4 && n801 == 2 && n156 == 4) {
            x = fx; w1 = fw1; w2 = big801[0]; w3 = big801[1]; w4 = fw4;
            g = bn156[0]; be = bn156[1]; mu = bn156[2]; va = bn156[3];
        }
    }
    float* out = (float*)d_out;

    // ws: [wq fp16 8.98MB][bias 2KB][bufA | bufB], each 64B/px NHWC padded.
    // chunk=64 needs 9MB + 2*64*1.08MB = 147MB.
    const size_t wqB   = (size_t)NB * WQH * 2;
    const size_t biasB = 2048;
    const size_t hdr   = wqB + biasB;
    const size_t perSlot = (size_t)PXS * 128;   // 2 buffers x 64B/px
    size_t avail = ws_size > hdr ? ws_size - hdr : 0;
    int chunk = (int)(avail / perSlot);
    if (chunk > NB) chunk = NB;
    if (chunk < 1)  chunk = 1;

    _Float16* wq   = (_Float16*)d_ws;
    float*    bias = (float*)((char*)d_ws + wqB);
    _Float16* bufA = (_Float16*)((char*)d_ws + hdr);
    _Float16* bufB = bufA + (size_t)chunk * PXS * 32;

    prep_w<<<2048, 256, 0, stream>>>(w1, w2, w3, w4, g, be, mu, va, wq, bias);

    for (int b0 = 0; b0 < NB; b0 += chunk) {
        int nb = (NB - b0 < chunk) ? (NB - b0) : chunk;
        pad_x<<<nb * 8, 256, 0, stream>>>(x, bufA, bufB, b0);
        int gc = nb * 16;
        dim3 g1(16, nb);
        // stage1: L0-L2 (x @ bufA ch0-9) -> bufB ch0-11
        stage3<1><<<gc, NTH, 0, stream>>>(bufA, bufB, wq,     0, bias,   0, b0);
        // stage2: L3-L5 (bufB: prev@0-11 + x@12-21) -> bufA ch0-11
        stage3<2><<<gc, NTH, 0, stream>>>(bufB, bufA, wq, 13824, bias,  96, b0);
        // stage3: L6-L8 -> bufB ch0-11
        stage3<2><<<gc, NTH, 0, stream>>>(bufA, bufB, wq, 41472, bias, 192, b0);
        // L9: 1x1, 22ch -> 11ch fp32
        conv1<<<g1, 256, 0, stream>>>(bufB, out, wq, 69120, b0);
    }
}